// Round 1
// baseline (387.387 us; speedup 1.0000x reference)
//
#include <hip/hip_runtime.h>
#include <hip/hip_bf16.h>
#include <cstdint>
#include <cstddef>

#define BB 2
#define SS 2048
#define EE 1024
#define HH 16
#define DD 64
#define MM (BB*SS)   // 4096

typedef __bf16 bf16;
typedef __bf16 bf16x8 __attribute__((ext_vector_type(8)));
typedef float f32x4 __attribute__((ext_vector_type(4)));

// ---------------- f32 -> bf16 convert ----------------
__global__ __launch_bounds__(256) void cvt_f32_bf16(const float* __restrict__ src,
                                                    bf16* __restrict__ dst, int n) {
    int i = (blockIdx.x * 256 + threadIdx.x) * 8;
    if (i >= n) return;
    float4 a = *(const float4*)(src + i);
    float4 b = *(const float4*)(src + i + 4);
    bf16 o[8] = {(bf16)a.x,(bf16)a.y,(bf16)a.z,(bf16)a.w,
                 (bf16)b.x,(bf16)b.y,(bf16)b.z,(bf16)b.w};
    *(uint4*)(dst + i) = *(uint4*)o;
}

// ---------------- GEMM: Y = A @ Wt^T + bias ----------------
// A: [M,K] bf16 row-major. Wt: [N,K] bf16 row-major (i.e. torch Linear weight).
// MODE 0: write bf16 to [B,H,S,D] layout (QKV). MODE 1: write f32 [M,N] flat.
template<int MODE>
__global__ __launch_bounds__(256) void gemm_bt(const bf16* __restrict__ A,
                                               const bf16* __restrict__ Wt,
                                               const float* __restrict__ bias,
                                               void* __restrict__ outp,
                                               int Kdim, int Ndim) {
    __shared__ bf16 Al[64][72];
    __shared__ bf16 Bl[64][72];
    const int t = threadIdx.x;
    const int m0 = blockIdx.y * 64, n0 = blockIdx.x * 64;
    const int w = t >> 6, lane = t & 63, lg = lane >> 4, li = lane & 15;
    const int wr = w >> 1, wc = w & 1;
    f32x4 acc[2][2] = {};
    for (int k0 = 0; k0 < Kdim; k0 += 64) {
        __syncthreads();
        for (int id = t; id < 512; id += 256) {
            int row = id >> 3, c = id & 7;
            *(uint4*)&Al[row][c*8] = *(const uint4*)&A [(size_t)(m0+row)*Kdim + k0 + c*8];
            *(uint4*)&Bl[row][c*8] = *(const uint4*)&Wt[(size_t)(n0+row)*Kdim + k0 + c*8];
        }
        __syncthreads();
        #pragma unroll
        for (int ks = 0; ks < 2; ++ks) {
            bf16x8 a0 = *(const bf16x8*)&Al[wr*32 +      li][ks*32 + lg*8];
            bf16x8 a1 = *(const bf16x8*)&Al[wr*32 + 16 + li][ks*32 + lg*8];
            bf16x8 b0 = *(const bf16x8*)&Bl[wc*32 +      li][ks*32 + lg*8];
            bf16x8 b1 = *(const bf16x8*)&Bl[wc*32 + 16 + li][ks*32 + lg*8];
            acc[0][0] = __builtin_amdgcn_mfma_f32_16x16x32_bf16(a0,b0,acc[0][0],0,0,0);
            acc[0][1] = __builtin_amdgcn_mfma_f32_16x16x32_bf16(a0,b1,acc[0][1],0,0,0);
            acc[1][0] = __builtin_amdgcn_mfma_f32_16x16x32_bf16(a1,b0,acc[1][0],0,0,0);
            acc[1][1] = __builtin_amdgcn_mfma_f32_16x16x32_bf16(a1,b1,acc[1][1],0,0,0);
        }
    }
    #pragma unroll
    for (int i = 0; i < 2; ++i)
      #pragma unroll
      for (int j = 0; j < 2; ++j)
        #pragma unroll
        for (int r = 0; r < 4; ++r) {
            int row = m0 + wr*32 + i*16 + lg*4 + r;
            int col = n0 + wc*32 + j*16 + li;
            float v = acc[i][j][r] + bias[col];
            if (MODE == 0) {
                int b = row >> 11, s = row & (SS-1);
                int h = col >> 6, d = col & 63;
                ((bf16*)outp)[(((size_t)(b*HH + h)*SS + s) << 6) + d] = (bf16)v;
            } else {
                ((float*)outp)[(size_t)row*Ndim + col] = v;
            }
        }
}

// ---------------- V transpose: [B*H][S][64] -> [B*H][64][S] ----------------
__global__ __launch_bounds__(256) void transpose_v(const bf16* __restrict__ V,
                                                   bf16* __restrict__ Vt) {
    __shared__ bf16 L[64][72];
    const int bh = blockIdx.y, s0 = blockIdx.x * 64, t = threadIdx.x;
    for (int id = t; id < 512; id += 256) {
        int row = id >> 3, c = id & 7;
        *(uint4*)&L[row][c*8] = *(const uint4*)&V[((size_t)bh*SS + s0 + row)*64 + c*8];
    }
    __syncthreads();
    for (int id = t; id < 512; id += 256) {
        int d = id >> 3, c = id & 7;
        bf16 tmp[8];
        #pragma unroll
        for (int jj = 0; jj < 8; ++jj) tmp[jj] = L[c*8 + jj][d];
        *(uint4*)&Vt[((size_t)bh*64 + d)*SS + s0 + c*8] = *(uint4*)tmp;
    }
}

// ---------------- fused ALiBi flash attention + weights materialization ----
// Q,K: [B*H][S][64] bf16; Vt: [B*H][64][S] bf16.
// wout: [B*H][S][S] f32 softmax weights. aout: [B][S][E] bf16 attention output.
__global__ __launch_bounds__(256) void attn_kernel(const bf16* __restrict__ Q,
                                                   const bf16* __restrict__ Kk,
                                                   const bf16* __restrict__ Vt,
                                                   float* __restrict__ wout,
                                                   bf16* __restrict__ aout) {
    __shared__ bf16 Qs[64][72], Ks[64][72], Vs[64][72];
    __shared__ bf16 Ps[4][16][72];
    const int qt = blockIdx.x, bh = blockIdx.y;
    const int b = bh >> 4, h = bh & 15;
    const int q0 = qt * 64;
    const int t = threadIdx.x, w = t >> 6, lane = t & 63, lg = lane >> 4, li = lane & 15;
    const float slope = exp2f(-(float)(h + 1));

    for (int id = t; id < 512; id += 256) {
        int row = id >> 3, c = id & 7;
        *(uint4*)&Qs[row][c*8] = *(const uint4*)&Q[((size_t)bh*SS + q0 + row)*64 + c*8];
    }
    __syncthreads();
    bf16x8 aq[2];
    aq[0] = *(const bf16x8*)&Qs[w*16 + li][     lg*8];
    aq[1] = *(const bf16x8*)&Qs[w*16 + li][32 + lg*8];

    float mrow[4], lrow[4];
    f32x4 acc[4] = {};
    #pragma unroll
    for (int r = 0; r < 4; ++r) { mrow[r] = -1e30f; lrow[r] = 0.f; }
    const float ibase = (float)(q0 + w*16 + lg*4);

    // ---- phase 1: flash loop (online softmax + PV) ----
    for (int kt = 0; kt < 32; ++kt) {
        const int j0 = kt * 64;
        __syncthreads();
        for (int id = t; id < 512; id += 256) {
            int row = id >> 3, c = id & 7;
            *(uint4*)&Ks[row][c*8] = *(const uint4*)&Kk[((size_t)bh*SS + j0 + row)*64 + c*8];
            *(uint4*)&Vs[row][c*8] = *(const uint4*)&Vt[((size_t)bh*64 + row)*SS + j0 + c*8];
        }
        __syncthreads();
        f32x4 sc[4] = {};
        #pragma unroll
        for (int cb = 0; cb < 4; ++cb)
            #pragma unroll
            for (int ks = 0; ks < 2; ++ks) {
                bf16x8 bk = *(const bf16x8*)&Ks[cb*16 + li][ks*32 + lg*8];
                sc[cb] = __builtin_amdgcn_mfma_f32_16x16x32_bf16(aq[ks], bk, sc[cb], 0,0,0);
            }
        float p[4][4];
        #pragma unroll
        for (int r = 0; r < 4; ++r) {
            float mx = -1e30f;
            #pragma unroll
            for (int cb = 0; cb < 4; ++cb) {
                float jf = (float)(j0 + cb*16 + li);
                float v = sc[cb][r]*0.125f + slope*(jf - (ibase + (float)r));
                sc[cb][r] = v;
                mx = fmaxf(mx, v);
            }
            mx = fmaxf(mx, __shfl_xor(mx, 1));
            mx = fmaxf(mx, __shfl_xor(mx, 2));
            mx = fmaxf(mx, __shfl_xor(mx, 4));
            mx = fmaxf(mx, __shfl_xor(mx, 8));
            float mnew = fmaxf(mrow[r], mx);
            float sf = __expf(mrow[r] - mnew);
            mrow[r] = mnew;
            float rs = 0.f;
            #pragma unroll
            for (int cb = 0; cb < 4; ++cb) {
                float e = __expf(sc[cb][r] - mnew);
                p[cb][r] = e;
                rs += e;
            }
            rs += __shfl_xor(rs, 1); rs += __shfl_xor(rs, 2);
            rs += __shfl_xor(rs, 4); rs += __shfl_xor(rs, 8);
            lrow[r] = lrow[r]*sf + rs;
            #pragma unroll
            for (int d0 = 0; d0 < 4; ++d0) acc[d0][r] *= sf;
        }
        #pragma unroll
        for (int cb = 0; cb < 4; ++cb)
            #pragma unroll
            for (int r = 0; r < 4; ++r)
                Ps[w][lg*4 + r][cb*16 + li] = (bf16)p[cb][r];
        #pragma unroll
        for (int ks = 0; ks < 2; ++ks) {
            bf16x8 ap = *(const bf16x8*)&Ps[w][li][ks*32 + lg*8];
            #pragma unroll
            for (int d0 = 0; d0 < 4; ++d0) {
                bf16x8 bv = *(const bf16x8*)&Vs[d0*16 + li][ks*32 + lg*8];
                acc[d0] = __builtin_amdgcn_mfma_f32_16x16x32_bf16(ap, bv, acc[d0], 0,0,0);
            }
        }
    }
    float rinv[4];
    #pragma unroll
    for (int r = 0; r < 4; ++r) rinv[r] = 1.f / lrow[r];
    #pragma unroll
    for (int d0 = 0; d0 < 4; ++d0)
        #pragma unroll
        for (int r = 0; r < 4; ++r) {
            int srow = q0 + w*16 + lg*4 + r;
            aout[((size_t)(b*SS + srow))*EE + h*64 + d0*16 + li] = (bf16)(acc[d0][r]*rinv[r]);
        }

    // ---- phase 2: recompute scores, write normalized weights ----
    for (int kt = 0; kt < 32; ++kt) {
        const int j0 = kt * 64;
        __syncthreads();
        for (int id = t; id < 512; id += 256) {
            int row = id >> 3, c = id & 7;
            *(uint4*)&Ks[row][c*8] = *(const uint4*)&Kk[((size_t)bh*SS + j0 + row)*64 + c*8];
        }
        __syncthreads();
        f32x4 sc[4] = {};
        #pragma unroll
        for (int cb = 0; cb < 4; ++cb)
            #pragma unroll
            for (int ks = 0; ks < 2; ++ks) {
                bf16x8 bk = *(const bf16x8*)&Ks[cb*16 + li][ks*32 + lg*8];
                sc[cb] = __builtin_amdgcn_mfma_f32_16x16x32_bf16(aq[ks], bk, sc[cb], 0,0,0);
            }
        #pragma unroll
        for (int cb = 0; cb < 4; ++cb)
            #pragma unroll
            for (int r = 0; r < 4; ++r) {
                float jf = (float)(j0 + cb*16 + li);
                float v = sc[cb][r]*0.125f + slope*(jf - (ibase + (float)r));
                int irow = q0 + w*16 + lg*4 + r;
                wout[((size_t)bh*SS + irow)*SS + j0 + cb*16 + li] = __expf(v - mrow[r]) * rinv[r];
            }
    }
}

// ---------------- launcher ----------------
extern "C" void kernel_launch(void* const* d_in, const int* in_sizes, int n_in,
                              void* d_out, int out_size, void* d_ws, size_t ws_size,
                              hipStream_t stream) {
    const float* x   = (const float*)d_in[0];
    const float* Wq  = (const float*)d_in[1];
    const float* bq  = (const float*)d_in[2];
    const float* Wk  = (const float*)d_in[3];
    const float* bk  = (const float*)d_in[4];
    const float* Wv  = (const float*)d_in[5];
    const float* bv  = (const float*)d_in[6];
    const float* Wfc = (const float*)d_in[7];
    const float* bfc = (const float*)d_in[8];

    char* ws = (char*)d_ws;
    const size_t MB = 1024u*1024u;
    bf16* xb  = (bf16*)(ws + 0);        // 8 MB
    bf16* wqb = (bf16*)(ws + 8*MB);     // 2 MB
    bf16* wkb = (bf16*)(ws + 10*MB);
    bf16* wvb = (bf16*)(ws + 12*MB);
    bf16* wfb = (bf16*)(ws + 14*MB);
    bf16* Qb  = (bf16*)(ws + 16*MB);    // 8 MB  [B*H][S][64]
    bf16* Kb  = (bf16*)(ws + 24*MB);    // 8 MB
    bf16* Vb  = (bf16*)(ws + 32*MB);    // 8 MB
    bf16* Vtb = (bf16*)(ws + 40*MB);    // 8 MB  [B*H][64][S]
    bf16* Ab  = (bf16*)(ws + 48*MB);    // 8 MB  [B][S][E]

    float* outp = (float*)d_out;
    float* wout = outp + (size_t)BB*SS*EE;

    cvt_f32_bf16<<<dim3(4194304/8/256), 256, 0, stream>>>(x,   xb,  4194304);
    cvt_f32_bf16<<<dim3(1048576/8/256), 256, 0, stream>>>(Wq,  wqb, 1048576);
    cvt_f32_bf16<<<dim3(1048576/8/256), 256, 0, stream>>>(Wk,  wkb, 1048576);
    cvt_f32_bf16<<<dim3(1048576/8/256), 256, 0, stream>>>(Wv,  wvb, 1048576);
    cvt_f32_bf16<<<dim3(1048576/8/256), 256, 0, stream>>>(Wfc, wfb, 1048576);

    dim3 gg(EE/64, MM/64);  // 16 x 64
    gemm_bt<0><<<gg, 256, 0, stream>>>(xb, wqb, bq, Qb, EE, EE);
    gemm_bt<0><<<gg, 256, 0, stream>>>(xb, wkb, bk, Kb, EE, EE);
    gemm_bt<0><<<gg, 256, 0, stream>>>(xb, wvb, bv, Vb, EE, EE);

    transpose_v<<<dim3(SS/64, BB*HH), 256, 0, stream>>>(Vb, Vtb);

    attn_kernel<<<dim3(SS/64, BB*HH), 256, 0, stream>>>(Qb, Kb, Vtb, wout, Ab);

    gemm_bt<1><<<gg, 256, 0, stream>>>(Ab, wfb, bfc, d_out, EE, EE);
}